// Round 2
// baseline (5068.201 us; speedup 1.0000x reference)
//
#include <hip/hip_runtime.h>
#include <cstdint>
#include <cstddef>

// ---------- constants ----------
#define CL 6
#define CH 12
#define CD 768
#define CDH 64
#define CF 3072
#define CV 32000
#define CS 1024
#define CB 2
#define CM (CB*CS)   // 2048 token rows

typedef unsigned short u16;
typedef __bf16 bf16x8 __attribute__((ext_vector_type(8)));
typedef float f32x4 __attribute__((ext_vector_type(4)));

__device__ __forceinline__ float bf2f(u16 u) {
  union { unsigned int i; float f; } c; c.i = ((unsigned int)u) << 16; return c.f;
}
__device__ __forceinline__ u16 f2bf(float f) {
  union { float f; unsigned int i; } c; c.f = f;
  unsigned int lsb = (c.i >> 16) & 1u;
  c.i += 0x7fffu + lsb;            // round-to-nearest-even
  return (u16)(c.i >> 16);
}

// ---------- fp32 -> bf16 convert (for head weight emb) ----------
__global__ __launch_bounds__(256) void convert_kernel(
    const float* __restrict__ src, u16* __restrict__ dst, int total)
{
  int idx = blockIdx.x * 256 + threadIdx.x;
  if (idx < total) dst[idx] = f2bf(src[idx]);
}

// ---------- embedding: x[m,d] = emb[X[m],d] + pos[s,d] (fp32 in/out) ----------
__global__ __launch_bounds__(256) void embed_kernel(
    const int* __restrict__ X, const float* __restrict__ emb,
    const float* __restrict__ pos, float* __restrict__ x)
{
  int idx = blockIdx.x * 256 + threadIdx.x;      // grid covers exactly CM*CD
  int m = idx / CD, d = idx - m * CD;
  int s = m & (CS - 1);
  x[idx] = emb[(size_t)X[m] * CD + d] + pos[s * CD + d];
}

// ---------- layernorm (fp32 in, bf16 out), one block per row ----------
__global__ __launch_bounds__(256) void ln_kernel(
    const float* __restrict__ x, const float* __restrict__ gs,
    const float* __restrict__ gb, u16* __restrict__ out)
{
  __shared__ float red[256];
  int row = blockIdx.x, tid = threadIdx.x;
  const float* xr = x + (size_t)row * CD;
  float s = 0.f;
  for (int i = tid; i < CD; i += 256) s += xr[i];
  red[tid] = s; __syncthreads();
  for (int st = 128; st > 0; st >>= 1) { if (tid < st) red[tid] += red[tid + st]; __syncthreads(); }
  float mu = red[0] * (1.f / CD); __syncthreads();
  float v = 0.f;
  for (int i = tid; i < CD; i += 256) { float d = xr[i] - mu; v += d * d; }
  red[tid] = v; __syncthreads();
  for (int st = 128; st > 0; st >>= 1) { if (tid < st) red[tid] += red[tid + st]; __syncthreads(); }
  float inv = rsqrtf(red[0] * (1.f / CD) + 1e-5f);
  u16* orow = out + (size_t)row * CD;
  for (int i = tid; i < CD; i += 256)
    orow[i] = f2bf((xr[i] - mu) * inv * gs[i] + gb[i]);
}

// ---------- transpose repack + downcast: dst[b][c][r] = bf16(src[b][r][c]) ----------
__global__ __launch_bounds__(256) void repackT_kernel(
    u16* __restrict__ dst, const float* __restrict__ src, int R, int C, int total)
{
  int idx = blockIdx.x * 256 + threadIdx.x;
  if (idx >= total) return;
  int rc = R * C;
  int bb = idx / rc, rem = idx - bb * rc;
  int c = rem / R, rr = rem - c * R;
  dst[idx] = f2bf(src[(size_t)bb * rc + (size_t)rr * C + c]);
}

// ---------- MFMA GEMM: C(MxN) = A(MxK,bf16) * Bt(NxK,bf16) + bias [+res][relu] ----------
// 64x64 tile, BK=32, 4 waves, mfma_f32_16x16x32_bf16.
template<bool RES, bool RELU, bool OUTBF>
__global__ __launch_bounds__(256) void gemm_kernel(
    const u16* __restrict__ A, const u16* __restrict__ Bt,
    const float* __restrict__ bias, const float* __restrict__ res,
    void* __restrict__ outp, int M, int N, int K)
{
  __shared__ __align__(16) u16 As[64 * 32];
  __shared__ __align__(16) u16 Bs[64 * 32];
  int tid = threadIdx.x;
  int m0 = blockIdx.y * 64, n0 = blockIdx.x * 64;
  int wid = tid >> 6, lane = tid & 63;
  int quad = lane >> 4, l16 = lane & 15;
  int wm = (wid >> 1) * 32, wn = (wid & 1) * 32;
  int r = tid >> 2, c8 = (tid & 3) * 8;     // staging: 64 rows x 32 cols, 8 bf16/thread

  f32x4 zero = {0.f, 0.f, 0.f, 0.f};
  f32x4 acc[2][2];
  acc[0][0] = zero; acc[0][1] = zero; acc[1][0] = zero; acc[1][1] = zero;

  for (int kt = 0; kt < K; kt += 32) {
    uint4 av = *(const uint4*)(A  + (size_t)(m0 + r) * K + kt + c8);
    uint4 bv = *(const uint4*)(Bt + (size_t)(n0 + r) * K + kt + c8);
    __syncthreads();
    *(uint4*)&As[r * 32 + c8] = av;
    *(uint4*)&Bs[r * 32 + c8] = bv;
    __syncthreads();
    bf16x8 af[2], bfr[2];
#pragma unroll
    for (int i = 0; i < 2; i++) {
      af[i]  = *reinterpret_cast<const bf16x8*>(&As[(wm + i * 16 + l16) * 32 + quad * 8]);
      bfr[i] = *reinterpret_cast<const bf16x8*>(&Bs[(wn + i * 16 + l16) * 32 + quad * 8]);
    }
#pragma unroll
    for (int i = 0; i < 2; i++)
#pragma unroll
      for (int j = 0; j < 2; j++)
        acc[i][j] = __builtin_amdgcn_mfma_f32_16x16x32_bf16(af[i], bfr[j], acc[i][j], 0, 0, 0);
  }

#pragma unroll
  for (int i = 0; i < 2; i++) {
    int gmb = m0 + wm + i * 16 + quad * 4;
#pragma unroll
    for (int j = 0; j < 2; j++) {
      int gn = n0 + wn + j * 16 + l16;
      float bsv = bias[gn];
#pragma unroll
      for (int rr = 0; rr < 4; rr++) {
        float val = acc[i][j][rr] + bsv;
        if (RELU) val = fmaxf(val, 0.f);
        size_t o = (size_t)(gmb + rr) * N + gn;
        if (RES) val += res[o];
        if (OUTBF) ((u16*)outp)[o] = f2bf(val);
        else       ((float*)outp)[o] = val;
      }
    }
  }
}

// ---------- attention: one block per (b,h,s); fp32 softmax ----------
__global__ __launch_bounds__(256) void attn_kernel(
    const u16* __restrict__ q, const u16* __restrict__ k,
    const u16* __restrict__ v, u16* __restrict__ o)
{
  int s = blockIdx.x, h = blockIdx.y, b = blockIdx.z;
  int tid = threadIdx.x;
  __shared__ float qs[CDH];
  __shared__ float sc[CS];
  __shared__ float red[256];
  __shared__ float part[4][CDH];
  size_t base = (size_t)b * CS * CD + (size_t)h * CDH;   // layout: [(b*S+s)*768 + h*64 + d]
  if (tid < CDH) qs[tid] = bf2f(q[base + (size_t)s * CD + tid]);
  __syncthreads();
  float lmax = -1e30f;
  for (int t = tid; t < CS; t += 256) {
    if (t <= s) {
      const uint4* k4 = (const uint4*)(k + base + (size_t)t * CD);
      float dot = 0.f;
#pragma unroll
      for (int jj = 0; jj < 8; jj++) {
        uint4 u = k4[jj];
        const u16* pu = (const u16*)&u;
#pragma unroll
        for (int e = 0; e < 8; e++) dot += qs[jj * 8 + e] * bf2f(pu[e]);
      }
      dot *= 0.125f;                 // 1/sqrt(64)
      sc[t] = dot;
      lmax = fmaxf(lmax, dot);
    } else {
      sc[t] = -1e30f;
    }
  }
  red[tid] = lmax; __syncthreads();
  for (int st = 128; st > 0; st >>= 1) { if (tid < st) red[tid] = fmaxf(red[tid], red[tid + st]); __syncthreads(); }
  float mx = red[0]; __syncthreads();
  float lsum = 0.f;
  for (int t = tid; t < CS; t += 256) {
    float p = (t <= s) ? __expf(sc[t] - mx) : 0.f;
    sc[t] = p; lsum += p;
  }
  red[tid] = lsum; __syncthreads();
  for (int st = 128; st > 0; st >>= 1) { if (tid < st) red[tid] += red[tid + st]; __syncthreads(); }
  float inv = 1.f / red[0];
  int d = tid & 63, tc = tid >> 6;
  float acc2 = 0.f;
  for (int t = tc; t <= s; t += 4) acc2 += sc[t] * bf2f(v[base + (size_t)t * CD + d]);
  part[tc][d] = acc2; __syncthreads();
  if (tid < CDH)
    o[base + (size_t)s * CD + tid] =
        f2bf((part[0][tid] + part[1][tid] + part[2][tid] + part[3][tid]) * inv);
}

// ---------- launcher ----------
extern "C" void kernel_launch(void* const* d_in, const int* in_sizes, int n_in,
                              void* d_out, int out_size, void* d_ws, size_t ws_size,
                              hipStream_t stream) {
  const int*   X      = (const int*)d_in[0];
  const float* emb    = (const float*)d_in[1];
  const float* pos    = (const float*)d_in[2];
  const float* Wq     = (const float*)d_in[3];
  const float* bq     = (const float*)d_in[4];
  const float* Wk     = (const float*)d_in[5];
  const float* bk     = (const float*)d_in[6];
  const float* Wv     = (const float*)d_in[7];
  const float* bv     = (const float*)d_in[8];
  const float* Wo     = (const float*)d_in[9];
  const float* bo     = (const float*)d_in[10];
  const float* ln1s   = (const float*)d_in[11];
  const float* ln1b   = (const float*)d_in[12];
  const float* ln2s   = (const float*)d_in[13];
  const float* ln2b   = (const float*)d_in[14];
  const float* W1     = (const float*)d_in[15];
  const float* b1     = (const float*)d_in[16];
  const float* W2     = (const float*)d_in[17];
  const float* b2     = (const float*)d_in[18];
  const float* lnfs   = (const float*)d_in[19];
  const float* lnfb   = (const float*)d_in[20];
  const float* headb  = (const float*)d_in[21];
  (void)in_sizes; (void)n_in; (void)out_size; (void)ws_size;

  char* ws = (char*)d_ws;
  size_t off = 0;
  auto alloc = [&](size_t bytes) { void* p = ws + off; off += (bytes + 255) & ~(size_t)255; return p; };

  float* x    = (float*)alloc((size_t)CM * CD * 4);
  u16*   xn   = (u16*)  alloc((size_t)CM * CD * 2);
  u16*   qb   = (u16*)  alloc((size_t)CM * CD * 2);
  u16*   kb   = (u16*)  alloc((size_t)CM * CD * 2);
  u16*   vb   = (u16*)  alloc((size_t)CM * CD * 2);
  u16*   ao   = (u16*)  alloc((size_t)CM * CD * 2);
  u16*   hb   = (u16*)  alloc((size_t)CM * CF * 2);
  u16*   Wqt  = (u16*)  alloc((size_t)CD * CD * 2);
  u16*   Wkt  = (u16*)  alloc((size_t)CD * CD * 2);
  u16*   Wvt  = (u16*)  alloc((size_t)CD * CD * 2);
  u16*   Wot  = (u16*)  alloc((size_t)CD * CD * 2);
  u16*   W1t  = (u16*)  alloc((size_t)CD * CF * 2);
  u16*   W2t  = (u16*)  alloc((size_t)CD * CF * 2);
  u16*   embC = (u16*)  alloc((size_t)CV * CD * 2);   // bf16 copy of emb for head GEMM

  embed_kernel<<<CM * CD / 256, 256, 0, stream>>>(X, emb, pos, x);
  convert_kernel<<<(CV * CD) / 256, 256, 0, stream>>>(emb, embC, CV * CD);

  const int QKV_TOT = CH * CD * CDH;        // 589824
  const int OO_TOT  = CD * CD;              // 589824
  const int FF_TOT  = CD * CF;              // 2359296

  for (int l = 0; l < CL; l++) {
    repackT_kernel<<<(QKV_TOT + 255) / 256, 256, 0, stream>>>(Wqt, Wq + (size_t)l * QKV_TOT, CD, CDH, QKV_TOT);
    repackT_kernel<<<(QKV_TOT + 255) / 256, 256, 0, stream>>>(Wkt, Wk + (size_t)l * QKV_TOT, CD, CDH, QKV_TOT);
    repackT_kernel<<<(QKV_TOT + 255) / 256, 256, 0, stream>>>(Wvt, Wv + (size_t)l * QKV_TOT, CD, CDH, QKV_TOT);
    repackT_kernel<<<(OO_TOT + 255) / 256, 256, 0, stream>>>(Wot, Wo + (size_t)l * OO_TOT, CD, CD, OO_TOT);
    repackT_kernel<<<(FF_TOT + 255) / 256, 256, 0, stream>>>(W1t, W1 + (size_t)l * FF_TOT, CD, CF, FF_TOT);
    repackT_kernel<<<(FF_TOT + 255) / 256, 256, 0, stream>>>(W2t, W2 + (size_t)l * FF_TOT, CF, CD, FF_TOT);

    ln_kernel<<<CM, 256, 0, stream>>>(x, ln1s + l * CD, ln1b + l * CD, xn);

    gemm_kernel<false, false, true><<<dim3(CD / 64, CM / 64), 256, 0, stream>>>(xn, Wqt, bq + l * CD, nullptr, qb, CM, CD, CD);
    gemm_kernel<false, false, true><<<dim3(CD / 64, CM / 64), 256, 0, stream>>>(xn, Wkt, bk + l * CD, nullptr, kb, CM, CD, CD);
    gemm_kernel<false, false, true><<<dim3(CD / 64, CM / 64), 256, 0, stream>>>(xn, Wvt, bv + l * CD, nullptr, vb, CM, CD, CD);

    attn_kernel<<<dim3(CS, CH, CB), 256, 0, stream>>>(qb, kb, vb, ao);

    gemm_kernel<true, false, false><<<dim3(CD / 64, CM / 64), 256, 0, stream>>>(ao, Wot, bo + l * CD, x, x, CM, CD, CD);

    ln_kernel<<<CM, 256, 0, stream>>>(x, ln2s + l * CD, ln2b + l * CD, xn);

    gemm_kernel<false, true, true><<<dim3(CF / 64, CM / 64), 256, 0, stream>>>(xn, W1t, b1 + l * CF, nullptr, hb, CM, CF, CD);
    gemm_kernel<true, false, false><<<dim3(CD / 64, CM / 64), 256, 0, stream>>>(hb, W2t, b2 + l * CD, x, x, CM, CD, CF);
  }

  ln_kernel<<<CM, 256, 0, stream>>>(x, lnfs, lnfb, xn);
  gemm_kernel<false, false, false><<<dim3(CV / 64, CM / 64), 256, 0, stream>>>(xn, embC, headb, nullptr, d_out, CM, CV, CD);
}